// Round 2
// baseline (263.855 us; speedup 1.0000x reference)
//
#include <hip/hip_runtime.h>

// Modular readout: 8 modules, each h = relu(x_m @ W1_m^T + b1_m); y_m = h @ W2_m^T + b2_m
// x [8192,4096] fp32; W1 [4096,4096] fp32 block-diag (8x 512x512); W2 [80,4096] fp32 block-diag (8x 10x512)
// out [8192,80] fp32 row-major (module-major columns).
//
// R2 design notes:
//  - R1 crashed (device fault): required 71.4 MB of d_ws without checking ws_size. Now adaptive:
//    ws_size >= 4MB -> pre-convert W1 diag blocks to bf16 (tier B); else fully in-kernel (tier C).
//  - x is converted fp32->bf16 AT STAGING (no separate pass, no workspace): less HBM than R1 plan.
//  - No global_load_lds this round (de-risk); plain vector loads + ds_write_b128.
//  - grid 512 = (tile<<3)|m so module m lands on XCD m (bid%8 round-robin) -> W1 block L2-resident.

#define NMOD 8
#define DIM 512
#define OSZ 10
#define BATCH 8192
#define D_IN 4096
#define D_OUT 80
#define BM 128
#define BK 32

typedef __attribute__((ext_vector_type(8))) short short8;   // 8 bf16 (4 VGPRs) MFMA A/B frag
typedef __attribute__((ext_vector_type(4))) float float4v;  // MFMA C/D frag

__device__ __forceinline__ unsigned short f2bf(float f) {
    unsigned int u = __builtin_bit_cast(unsigned int, f);
    u += 0x7fffu + ((u >> 16) & 1u);   // RNE
    return (unsigned short)(u >> 16);
}

__device__ __forceinline__ short8 cvt8(float4 a, float4 b) {
    short8 r;
    r[0] = (short)f2bf(a.x); r[1] = (short)f2bf(a.y); r[2] = (short)f2bf(a.z); r[3] = (short)f2bf(a.w);
    r[4] = (short)f2bf(b.x); r[5] = (short)f2bf(b.y); r[6] = (short)f2bf(b.z); r[7] = (short)f2bf(b.w);
    return r;
}

// ------- tier B only: gather W1 diag blocks -> w1b[8][512][512] bf16 -------
__global__ void cvt_w_kernel(const float* __restrict__ W1, ushort* __restrict__ w1b) {
    int j = blockIdx.x * 256 + threadIdx.x;          // 2048*256 = 524288 float4 jobs
    int mm = j >> 16, rem = j & 65535, r = rem >> 7, c4 = rem & 127;
    float4 v = *(const float4*)(W1 + (size_t)(mm * DIM + r) * D_IN + mm * DIM + c4 * 4);
    *(ushort4*)(w1b + (size_t)mm * DIM * DIM + r * DIM + c4 * 4) =
        make_ushort4(f2bf(v.x), f2bf(v.y), f2bf(v.z), f2bf(v.w));
}

// ---------------- fused kernel ----------------
// grid 512 (64 row-tiles x 8 modules), block 512 (8 waves). WG tile: 128 rows x 512 hidden.
// Wave w: hidden cols [w*64, w*64+64), acc[8][4] float4 = 128 VGPR.
// LDS 80 KB: staging A[128][32]bf16 @0 (8K) + B[512][32]bf16 @8K (32K);
//            ldsH [64][512]bf16 @0 (64K, aliased post-K-loop, XOR-swizzled);
//            ldsW2 [16][512]bf16 @64K (16K, XOR-swizzled, rows 10..15 zero).
template <bool WPRE>
__global__ __launch_bounds__(512, 2)
void fused_kernel(const float* __restrict__ x, const float* __restrict__ W1,
                  const ushort* __restrict__ w1b, const float* __restrict__ b1,
                  const float* __restrict__ W2, const float* __restrict__ b2,
                  float* __restrict__ out) {
    __shared__ ushort smem[40960];            // 80 KB
    ushort* ldsA  = smem;                     // [128][32]
    ushort* ldsB  = smem + 4096;              // [512][32]
    ushort* ldsH  = smem;                     // [64][512] swizzled
    ushort* ldsW2 = smem + 32768;             // [16][512] swizzled

    const int tid  = threadIdx.x;
    const int wave = tid >> 6;
    const int lane = tid & 63;
    const int r16  = lane & 15;
    const int kq   = lane >> 4;

    const int bid     = blockIdx.x;
    const int m       = bid & 7;              // module -> XCD affinity
    const int rowBase = (bid >> 3) * BM;

    // ---- stage W2 block (10x512 fp32 -> bf16, pad to 16 rows) into ldsW2, once ----
    {
        const int row = tid >> 5;             // 0..15
        const int col = (tid & 31) * 16;      // 0..496
        short8 v0 = {0, 0, 0, 0, 0, 0, 0, 0};
        short8 v1 = {0, 0, 0, 0, 0, 0, 0, 0};
        if (row < OSZ) {
            const float* s = W2 + (size_t)(m * OSZ + row) * D_IN + m * DIM + col;
            v0 = cvt8(*(const float4*)s, *(const float4*)(s + 4));
            v1 = cvt8(*(const float4*)(s + 8), *(const float4*)(s + 12));
        }
        const int sw = (row & 7) << 3;
        *(short8*)(ldsW2 + row * DIM + (col ^ sw))       = v0;
        *(short8*)(ldsW2 + row * DIM + ((col + 8) ^ sw)) = v1;
    }

    const float*  xsrc = x + (size_t)rowBase * D_IN + m * DIM;       // row stride D_IN
    const ushort* w1m  = w1b + (size_t)m * DIM * DIM;                // bf16 [512][512]
    const float*  w1f  = W1 + (size_t)(m * DIM) * D_IN + m * DIM;    // fp32, row stride D_IN

    float4v acc[8][4];
#pragma unroll
    for (int i = 0; i < 8; i++)
#pragma unroll
        for (int j = 0; j < 4; j++) acc[i][j] = (float4v){0.f, 0.f, 0.f, 0.f};

    const int arow = tid >> 2;                // 0..127
    const int akc  = tid & 3;                 // k-chunk of 8

    for (int kk = 0; kk < DIM / BK; kk++) {
        const int k0 = kk * BK;
        // ---- stage A: x fp32 -> bf16, 128x32 ----
        {
            const float* s = xsrc + (size_t)arow * D_IN + k0 + akc * 8;
            *(short8*)(ldsA + arow * BK + akc * 8) = cvt8(*(const float4*)s, *(const float4*)(s + 4));
        }
        // ---- stage B: W1 block, 512x32 ----
        if (WPRE) {
#pragma unroll
            for (int r = 0; r < 4; r++) {
                short8 v = *(const short8*)(w1m + (size_t)(r * 128 + arow) * DIM + k0 + akc * 8);
                *(short8*)(ldsB + (r * 128 + arow) * BK + akc * 8) = v;
            }
        } else {
#pragma unroll
            for (int r = 0; r < 4; r++) {
                const float* s = w1f + (size_t)(r * 128 + arow) * D_IN + k0 + akc * 8;
                *(short8*)(ldsB + (r * 128 + arow) * BK + akc * 8) =
                    cvt8(*(const float4*)s, *(const float4*)(s + 4));
            }
        }
        __syncthreads();

        short8 aF[8], bF[4];
#pragma unroll
        for (int mt = 0; mt < 8; mt++)
            aF[mt] = *(const short8*)(ldsA + (mt * 16 + r16) * BK + kq * 8);
#pragma unroll
        for (int nt = 0; nt < 4; nt++)
            bF[nt] = *(const short8*)(ldsB + (wave * 64 + nt * 16 + r16) * BK + kq * 8);
#pragma unroll
        for (int mt = 0; mt < 8; mt++)
#pragma unroll
            for (int nt = 0; nt < 4; nt++)
                acc[mt][nt] = __builtin_amdgcn_mfma_f32_16x16x32_bf16(aF[mt], bF[nt], acc[mt][nt], 0, 0, 0);
        __syncthreads();
    }

    float b1v[4];
#pragma unroll
    for (int nt = 0; nt < 4; nt++)
        b1v[nt] = b1[m * DIM + wave * 64 + nt * 16 + r16];

    // ---- epilogue: two 64-row halves; h -> ldsH (bias+relu, bf16, swizzled); layer 2 ----
    for (int hh = 0; hh < 2; hh++) {
#pragma unroll
        for (int mt2 = 0; mt2 < 4; mt2++) {
            const int mt = hh * 4 + mt2;
#pragma unroll
            for (int nt = 0; nt < 4; nt++) {
#pragma unroll
                for (int reg = 0; reg < 4; reg++) {
                    float v = acc[mt][nt][reg] + b1v[nt];
                    v = v > 0.f ? v : 0.f;
                    const int lr  = mt2 * 16 + kq * 4 + reg;         // batch row (D row = quad*4+reg)
                    const int col = wave * 64 + nt * 16 + r16;       // hidden col
                    ldsH[lr * DIM + (col ^ ((lr & 7) << 3))] = f2bf(v);
                }
            }
        }
        __syncthreads();

        if (wave < 4) {   // layer 2: y[64x10] = h @ W2^T (N padded to 16)
            float4v acc2 = (float4v){0.f, 0.f, 0.f, 0.f};
            const int hrow = wave * 16 + r16;
            const int hsw  = (hrow & 7) << 3;
            const int wsw  = (r16 & 7) << 3;
#pragma unroll
            for (int kk2 = 0; kk2 < 16; kk2++) {
                const int col = kk2 * 32 + kq * 8;
                short8 ha = *(const short8*)(ldsH + hrow * DIM + (col ^ hsw));
                short8 wb = *(const short8*)(ldsW2 + r16 * DIM + (col ^ wsw));
                acc2 = __builtin_amdgcn_mfma_f32_16x16x32_bf16(ha, wb, acc2, 0, 0, 0);
            }
            if (r16 < OSZ) {
                const float b2v = b2[m * OSZ + r16];
#pragma unroll
                for (int reg = 0; reg < 4; reg++) {
                    const int grow = rowBase + hh * 64 + wave * 16 + kq * 4 + reg;
                    out[(size_t)grow * D_OUT + m * OSZ + r16] = acc2[reg] + b2v;
                }
            }
        }
        __syncthreads();   // ldsH rewritten in next half
    }
}

extern "C" void kernel_launch(void* const* d_in, const int* in_sizes, int n_in,
                              void* d_out, int out_size, void* d_ws, size_t ws_size,
                              hipStream_t stream) {
    const float* x  = (const float*)d_in[0];
    const float* W1 = (const float*)d_in[1];
    const float* b1 = (const float*)d_in[2];
    const float* W2 = (const float*)d_in[3];
    const float* b2 = (const float*)d_in[4];
    float* out = (float*)d_out;

    if (ws_size >= (size_t)NMOD * DIM * DIM * sizeof(ushort)) {   // 4 MB: tier B
        ushort* w1b = (ushort*)d_ws;
        cvt_w_kernel<<<dim3(2048), dim3(256), 0, stream>>>(W1, w1b);
        fused_kernel<true><<<dim3(512), dim3(512), 0, stream>>>(x, W1, w1b, b1, W2, b2, out);
    } else {                                                      // tier C: zero workspace
        fused_kernel<false><<<dim3(512), dim3(512), 0, stream>>>(x, W1, nullptr, b1, W2, b2, out);
    }
}